// Round 4
// baseline (2282.683 us; speedup 1.0000x reference)
//
#include <hip/hip_runtime.h>

// CRF negative log-likelihood, B=128, T=1024, NT=254, N=256.
// 8 blocks x 16 batches; 256 threads = 4 waves. Step = 256x256 * 256x16 GEMM
// via mfma_f32_16x16x32_bf16, E=exp(trans) resident in A-fragments (VGPRs).
// State S (256 states x 16 cols, bf16) in LDS, 528B col stride (conflict-free).
// Power-of-2 normalization from one-step-lagged cross-wave max (exact exponent
// bookkeeping in Ms). Two raw s_barriers/step; unary prefetch depth 2 stays in
// flight across barriers. Per-column snapshot at t==len-1 handles lengths.

typedef __attribute__((ext_vector_type(8))) short bf16x8;   // 8 bf16 (4 VGPR)
typedef __attribute__((ext_vector_type(4))) float f32x4;

constexpr int   B_ = 128, T_ = 1024, NT_ = 254, N_ = 256;
constexpr int   START_ = 254, END_ = 255;
constexpr float NEGV = -10000.0f;
constexpr float RLN2 = 1.44269504088896340736f;  // 1/ln2
constexpr float LN2f = 0.69314718055994530942f;
constexpr int   NB = 16;     // batches per block
constexpr int   CS = 528;    // LDS column stride in bytes (33*16 -> conflict-free)

// barrier that does NOT drain vmcnt: LDS-ordered only.
#define BAR() asm volatile("s_waitcnt lgkmcnt(0)\n\ts_barrier" ::: "memory")

__device__ __forceinline__ unsigned short f2bf(float f) {  // f32 -> bf16 RNE
  unsigned u = __builtin_bit_cast(unsigned, f);
  return (unsigned short)((u + 0x7FFFu + ((u >> 16) & 1u)) >> 16);
}

__global__ __launch_bounds__(256, 1) void crf_fwd(
    const float* __restrict__ unary, const int* __restrict__ tags,
    const int* __restrict__ lengths, const float* __restrict__ trans,
    float* __restrict__ out)
{
  const int tid = threadIdx.x;
  const int w = tid >> 6, l = tid & 63;
  const int c = l & 15;      // column (batch-in-block); also A-row / D-col
  const int h = l >> 4;      // lane group: k-offset for A/B, row-group for D
  const int bb = blockIdx.x * NB;

  __shared__ alignas(16) unsigned char Sb[NB * CS];  // S_T[col][k] bf16
  __shared__ float wmaxb[2][4][NB];                  // lagged per-col max
  __shared__ float redP[4][NB], redG[4][NB];

  const int lenc = lengths[bb + c];
  int ml = lenc;
#pragma unroll
  for (int o = 1; o < 16; o <<= 1) ml = max(ml, __shfl_xor(ml, o, 64));
  const int Tmax = (ml + 1) & ~1;       // even # steps; extra step harmless
  const int lenm1 = lenc - 1;

  // ---- A fragments: E = exp(trans), resident in VGPRs ----
  bf16x8 Af[4][8];
#pragma unroll
  for (int tile = 0; tile < 4; ++tile) {
    const float* tr = trans + (size_t)((w * 4 + tile) * 16 + c) * N_;
#pragma unroll
    for (int kk = 0; kk < 8; ++kk) {
      const float* p = tr + kk * 32 + h * 8;
      bf16x8 a;
#pragma unroll
      for (int e2 = 0; e2 < 8; ++e2) a[e2] = (short)f2bf(__expf(p[e2]));
      Af[tile][kk] = a;
    }
  }

  // ---- init S (1.0 at state START, col-wise) and wmax ----
#pragma unroll
  for (int tile = 0; tile < 4; ++tile) {
    int rb = (w * 4 + tile) * 16 + h * 4;
    unsigned long long v = 0ull;
    if (rb == 252) v = 0x00003F8000000000ull;  // row 254 = bf16 1.0 (r=2 slot)
    *(unsigned long long*)(Sb + c * CS + 2 * rb) = v;
  }
  if (l < 16) wmaxb[0][w][l] = 1.0f;

  // ---- gold partial: thread (c, slice) handles t = slice, slice+16, ... ----
  float gold = 0.f;
  {
    const int slice = tid >> 4;  // w*4+h, 0..15
    const int* tg = tags + (size_t)(bb + c) * T_;
    const float* ug = unary + (size_t)(bb + c) * T_ * NT_;
    for (int q = 0; q < 64; ++q) {
      int t = slice + (q << 4);
      if (t >= lenc) break;
      int curr = tg[t];
      int prev = t ? tg[t - 1] : START_;
      gold += trans[curr * N_ + prev] + ug[(size_t)t * NT_ + curr];
    }
  }

  // ---- unary prefetch (per-lane rows of its D fragment, col c) ----
  auto loadU = [&](int t, float2 (&dst)[4][2]) {
    const float* ug = unary + ((size_t)(bb + c) * T_ + t) * NT_;
#pragma unroll
    for (int tile = 0; tile < 4; ++tile) {
      int rb = (w * 4 + tile) * 16 + h * 4;
      if (rb == 252) {  // rows 252,253 real; 254,255 are START/END -> NEG
        dst[tile][0] = *(const float2*)(ug + 252);
        dst[tile][1] = make_float2(NEGV, NEGV);
      } else {
        dst[tile][0] = *(const float2*)(ug + rb);
        dst[tile][1] = *(const float2*)(ug + rb + 2);
      }
    }
  };

  float Ms = 0.f, Msnap = 0.f;
  float snap[4][4] = {};
  float2 uA[4][2], uB[4][2];
  loadU(0, uA);
  loadU(1, uB);

#define STEP(T, SR, SW, UN)                                                    \
  {                                                                            \
    float2 nf[4][2];                                                           \
    bool pf = (T) + 2 < Tmax;                                                  \
    if (pf) loadU((T) + 2, nf); /* stays in flight across barriers */          \
    BAR(); /* B1: prior step's S/wmax writes visible */                        \
    bf16x8 Bf[8];                                                              \
    _Pragma("unroll")                                                          \
    for (int kk = 0; kk < 8; ++kk)                                             \
      Bf[kk] = *(const bf16x8*)(Sb + c * CS + kk * 64 + h * 16);               \
    float m0 = wmaxb[SR][0][c], m1 = wmaxb[SR][1][c],                          \
          m2 = wmaxb[SR][2][c], m3 = wmaxb[SR][3][c];                          \
    BAR(); /* B2: all waves' reads done -> writes may proceed */               \
    f32x4 acc0 = {0,0,0,0}, acc1 = {0,0,0,0}, acc2 = {0,0,0,0},                \
          acc3 = {0,0,0,0};                                                    \
    _Pragma("unroll")                                                          \
    for (int kk = 0; kk < 8; ++kk) {                                           \
      acc0 = __builtin_amdgcn_mfma_f32_16x16x32_bf16(Af[0][kk], Bf[kk], acc0, 0, 0, 0); \
      acc1 = __builtin_amdgcn_mfma_f32_16x16x32_bf16(Af[1][kk], Bf[kk], acc1, 0, 0, 0); \
      acc2 = __builtin_amdgcn_mfma_f32_16x16x32_bf16(Af[2][kk], Bf[kk], acc2, 0, 0, 0); \
      acc3 = __builtin_amdgcn_mfma_f32_16x16x32_bf16(Af[3][kk], Bf[kk], acc3, 0, 0, 0); \
    }                                                                          \
    float m = fmaxf(fmaxf(m0, m1), fmaxf(m2, m3));                             \
    unsigned mb = __builtin_bit_cast(unsigned, m);                             \
    int eb = (int)((mb >> 23) & 0xFFu);                                        \
    eb = eb < 1 ? 1 : (eb > 253 ? 253 : eb);                                   \
    float scale = __builtin_bit_cast(float, (unsigned)((254 - eb) << 23));     \
    Ms += (float)(eb - 127);                                                   \
    float sv[4][4]; float mx = 0.f;                                            \
    _Pragma("unroll")                                                          \
    for (int tile = 0; tile < 4; ++tile) {                                     \
      f32x4 A_ = tile == 0 ? acc0 : tile == 1 ? acc1 : tile == 2 ? acc2 : acc3;\
      _Pragma("unroll")                                                        \
      for (int r = 0; r < 4; ++r) {                                            \
        float uu = r < 2 ? (r == 0 ? UN[tile][0].x : UN[tile][0].y)            \
                         : (r == 2 ? UN[tile][1].x : UN[tile][1].y);           \
        float eu = __builtin_exp2f(uu * RLN2);                                 \
        float s1 = A_[r] * eu * scale;                                         \
        sv[tile][r] = s1; mx = fmaxf(mx, s1);                                  \
      }                                                                        \
      unsigned p0 = ((unsigned)f2bf(sv[tile][0])) |                            \
                    ((unsigned)f2bf(sv[tile][1]) << 16);                       \
      unsigned p1 = ((unsigned)f2bf(sv[tile][2])) |                            \
                    ((unsigned)f2bf(sv[tile][3]) << 16);                       \
      unsigned long long pk = ((unsigned long long)p1 << 32) | p0;             \
      *(unsigned long long*)(Sb + c * CS + 2 * ((w * 4 + tile) * 16 + h * 4)) = pk; \
    }                                                                          \
    if ((T) == lenm1) {                                                        \
      Msnap = Ms;                                                              \
      _Pragma("unroll") for (int i2 = 0; i2 < 4; ++i2)                         \
      _Pragma("unroll") for (int r2 = 0; r2 < 4; ++r2)                         \
        snap[i2][r2] = sv[i2][r2];                                             \
    }                                                                          \
    mx = fmaxf(mx, __shfl_xor(mx, 16, 64));                                    \
    mx = fmaxf(mx, __shfl_xor(mx, 32, 64));                                    \
    if (l < 16) wmaxb[SW][w][l] = mx;                                          \
    if (pf) {                                                                  \
      _Pragma("unroll") for (int i3 = 0; i3 < 4; ++i3) {                       \
        UN[i3][0] = nf[i3][0]; UN[i3][1] = nf[i3][1];                          \
      }                                                                        \
    }                                                                          \
  }

  for (int t = 0; t < Tmax; t += 2) {
    STEP(t,     0, 1, uA)
    STEP(t + 1, 1, 0, uB)
  }
#undef STEP

  // ---- fwd_c = ln2*(Msnap + log2(sum_j snap_j * 2^(trans[end,j]/ln2))) ----
  float P = 0.f;
#pragma unroll
  for (int tile = 0; tile < 4; ++tile) {
    int rb = (w * 4 + tile) * 16 + h * 4;
    const float* tE = trans + (size_t)END_ * N_ + rb;
#pragma unroll
    for (int r = 0; r < 4; ++r)
      P += snap[tile][r] * __builtin_exp2f(tE[r] * RLN2);
  }
  P += __shfl_xor(P, 16, 64); P += __shfl_xor(P, 32, 64);
  float G = gold;
  G += __shfl_xor(G, 16, 64); G += __shfl_xor(G, 32, 64);
  if (l < 16) { redP[w][l] = P; redG[w][l] = G; }
  __syncthreads();
  if (w == 0 && l < 16) {
    float Ss = redP[0][l] + redP[1][l] + redP[2][l] + redP[3][l];
    float Gs = redG[0][l] + redG[1][l] + redG[2][l] + redG[3][l];
    int last = tags[(size_t)(bb + l) * T_ + lenm1];
    float fwd = LN2f * (Msnap + __log2f(Ss));
    out[bb + l] = fwd - (Gs + trans[(size_t)END_ * N_ + last]);
  }
}

extern "C" void kernel_launch(void* const* d_in, const int* in_sizes, int n_in,
                              void* d_out, int out_size, void* d_ws, size_t ws_size,
                              hipStream_t stream) {
  const float* unary   = (const float*)d_in[0];
  const int*   tags    = (const int*)d_in[1];
  const int*   lengths = (const int*)d_in[2];
  const float* trans   = (const float*)d_in[3];
  float*       out     = (float*)d_out;
  hipLaunchKernelGGL(crf_fwd, dim3(B_ / NB), dim3(256), 0, stream,
                     unary, tags, lengths, trans, out);
}

// Round 6
// 827.151 us; speedup vs baseline: 2.7597x; 2.7597x over previous
//
#include <hip/hip_runtime.h>

// CRF negative log-likelihood, B=128, T=1024, NT=254, N=256.
// ONE block per batch (128 blocks -> 128 CUs), 256 threads = 4 waves.
// Step = 256x256 matvec done as mfma_f32_16x16x32_bf16 with all 16 B-columns
// carrying the same state vector (systolic broadcast replaces the R1/R2 LDS
// broadcast wall; column utilization is irrelevant, latency is the game).
// Wave w owns output rows w*64..w*64+63 (4 row-tiles x 8 k-tiles = 32 MFMA).
// E = exp(trans) resident in A-fragments (128 VGPR/lane). State S double-
// buffered in LDS (2x512B, bf16); ONE raw s_barrier per step. Power-of-2
// normalization from one-step-lagged per-(wave,q) maxes (exact exponent
// bookkeeping in Ms, scheme verified absmax=0.0 in R4). Unary prefetch
// depth 2, float2 loads, reloaded in place (unroll-2 alternation).

typedef __attribute__((ext_vector_type(8))) short bf16x8;   // 8 bf16 (4 VGPR)
typedef __attribute__((ext_vector_type(4))) float f32x4;

constexpr int   B_ = 128, T_ = 1024, NT_ = 254, N_ = 256;
constexpr int   START_ = 254, END_ = 255;
constexpr float NEGV = -10000.0f;
constexpr float RLN2 = 1.44269504088896340736f;  // 1/ln2
constexpr float LN2f = 0.69314718055994530942f;

// barrier that does NOT drain vmcnt: LDS-ordered only.
#define BAR() asm volatile("s_waitcnt lgkmcnt(0)\n\ts_barrier" ::: "memory")

__device__ __forceinline__ unsigned short f2bf(float f) {  // f32 -> bf16 RNE
  unsigned u = __builtin_bit_cast(unsigned, f);
  return (unsigned short)((u + 0x7FFFu + ((u >> 16) & 1u)) >> 16);
}

// fmax with DPP quad_perm partner (ctrl must be a compile-time constant).
template <int CTRL>
__device__ __forceinline__ float dppmax_quad(float x) {
  float t = __builtin_bit_cast(float,
      __builtin_amdgcn_update_dpp(__builtin_bit_cast(int, x),
                                  __builtin_bit_cast(int, x),
                                  CTRL, 0xF, 0xF, false));
  return fmaxf(x, t);
}

__global__ __launch_bounds__(256, 1) void crf_fwd(
    const float* __restrict__ unary, const int* __restrict__ tags,
    const int* __restrict__ lengths, const float* __restrict__ trans,
    float* __restrict__ out)
{
  const int tid = threadIdx.x;
  const int w = tid >> 6, l = tid & 63;
  const int c = l & 15;      // MFMA col (all cols identical); picks row-tile
  const int q = l >> 4;      // k-group for A/B, row-group for D
  const int b = blockIdx.x;
  const int len = lengths[b];             // 1..T

  __shared__ alignas(16) short Sb[2][N_];        // state, bf16, double-buffered
  __shared__ alignas(16) float wmaxb[2][4][4];   // [buf][wave][q] lagged maxes
  __shared__ float redP[4], redG[4];

  // ---- A fragments: E = exp(trans), resident in VGPRs ----
  // A layout (R4-verified): row = lane&15 within tile, k = (lane>>4)*8 + e.
  bf16x8 Af[4][8];
#pragma unroll
  for (int tile = 0; tile < 4; ++tile) {
    const float* tr = trans + (size_t)(w * 64 + tile * 16 + c) * N_;
#pragma unroll
    for (int kk = 0; kk < 8; ++kk) {
      const float4* p4 = reinterpret_cast<const float4*>(tr + kk * 32 + q * 8);
      float4 x0 = p4[0], x1 = p4[1];
      bf16x8 a;
      a[0] = (short)f2bf(__expf(x0.x)); a[1] = (short)f2bf(__expf(x0.y));
      a[2] = (short)f2bf(__expf(x0.z)); a[3] = (short)f2bf(__expf(x0.w));
      a[4] = (short)f2bf(__expf(x1.x)); a[5] = (short)f2bf(__expf(x1.y));
      a[6] = (short)f2bf(__expf(x1.z)); a[7] = (short)f2bf(__expf(x1.w));
      Af[tile][kk] = a;
    }
  }

  const float* ub = unary + (size_t)b * T_ * NT_;

  // ---- gold partial: thread tid handles t = tid, tid+256, tid+512, tid+768 ----
  float gold = 0.f;
#pragma unroll
  for (int qq = 0; qq < 4; ++qq) {
    int t = tid + qq * 256;
    if (t < len) {
      int curr = tags[b * T_ + t];
      int prev = t ? tags[b * T_ + t - 1] : START_;
      gold += trans[curr * N_ + prev] + ub[(size_t)t * NT_ + curr];
    }
  }

  // ---- init: s0 = 1.0 at START else 0; lagged maxes = 1.0 ----
  Sb[0][tid] = (tid == START_) ? (short)0x3F80 : (short)0;
  if (l < 4) wmaxb[0][w][l] = 1.0f;

  // ---- writer-lane geometry: lanes c<4 write rows rowbase..rowbase+3 ----
  const bool wr = (c < 4);
  const int rowbase = w * 64 + c * 16 + q * 4;
  const bool edge = (rowbase == 252);   // rows 252,253 real; 254,255 -> NEG

  auto loadU = [&](int t, float4& dst) {
    const float* ugp = ub + (size_t)t * NT_ + rowbase;   // 8B-aligned always
    float2 lo = *reinterpret_cast<const float2*>(ugp);
    float2 hi = edge ? make_float2(NEGV, NEGV)
                     : *reinterpret_cast<const float2*>(ugp + 2);
    dst = make_float4(lo.x, lo.y, hi.x, hi.y);
  };

  float4 uA = make_float4(NEGV, NEGV, NEGV, NEGV), uB = uA;
  if (wr) { loadU(0, uA); loadU(1, uB); }   // T_=1024 >= 2, always in-bounds

  float Ms = 0.f;
  float sf0 = 0.f, sf1 = 0.f, sf2 = 0.f, sf3 = 0.f;  // final-state regs

  auto step = [&](int T, float4& UN) {
    const int cb = T & 1, nb = cb ^ 1;
    BAR();  // publishes prev step's S/wmax writes; vmcnt stays in flight

    // lagged max of current s-buffer (16 per-(wave,q) values, uniform reads)
    float4 wmA = *reinterpret_cast<const float4*>(wmaxb[cb][0]);
    float4 wmB = *reinterpret_cast<const float4*>(wmaxb[cb][1]);
    float4 wmC = *reinterpret_cast<const float4*>(wmaxb[cb][2]);
    float4 wmD = *reinterpret_cast<const float4*>(wmaxb[cb][3]);

    // B-frag reads: uniform per 16-lane group (broadcast, conflict-free) + MFMA
    const char* sbase = reinterpret_cast<const char*>(&Sb[cb][0]) + q * 16;
    f32x4 a0 = {0,0,0,0}, a1 = {0,0,0,0}, a2 = {0,0,0,0}, a3 = {0,0,0,0};
#pragma unroll
    for (int kk = 0; kk < 8; ++kk) {
      bf16x8 Bk = *reinterpret_cast<const bf16x8*>(sbase + kk * 64);
      a0 = __builtin_amdgcn_mfma_f32_16x16x32_bf16(Af[0][kk], Bk, a0, 0, 0, 0);
      a1 = __builtin_amdgcn_mfma_f32_16x16x32_bf16(Af[1][kk], Bk, a1, 0, 0, 0);
      a2 = __builtin_amdgcn_mfma_f32_16x16x32_bf16(Af[2][kk], Bk, a2, 0, 0, 0);
      a3 = __builtin_amdgcn_mfma_f32_16x16x32_bf16(Af[3][kk], Bk, a3, 0, 0, 0);
    }

    // scale = 2^(127-eb(m)); Ms += eb-127  (exact, R4-verified scheme)
    float mA = fmaxf(fmaxf(wmA.x, wmA.y), fmaxf(wmA.z, wmA.w));
    float mB = fmaxf(fmaxf(wmB.x, wmB.y), fmaxf(wmB.z, wmB.w));
    float mC = fmaxf(fmaxf(wmC.x, wmC.y), fmaxf(wmC.z, wmC.w));
    float mD = fmaxf(fmaxf(wmD.x, wmD.y), fmaxf(wmD.z, wmD.w));
    float m  = fmaxf(fmaxf(mA, mB), fmaxf(mC, mD));
    unsigned mb = __builtin_bit_cast(unsigned, m);
    int eb = (int)((mb >> 23) & 0xFFu);
    eb = eb < 1 ? 1 : (eb > 253 ? 253 : eb);
    float scale = __builtin_bit_cast(float, (unsigned)((254 - eb) << 23));
    Ms += (float)(eb - 127);

    if (wr) {
      float e0 = __builtin_exp2f(UN.x * RLN2) * scale;
      float e1 = __builtin_exp2f(UN.y * RLN2) * scale;
      float e2 = __builtin_exp2f(UN.z * RLN2) * scale;
      float e3 = __builtin_exp2f(UN.w * RLN2) * scale;
      f32x4 sel = a3;                 // pick this lane's row-tile (c = tile)
      sel = (c == 2) ? a2 : sel;
      sel = (c == 1) ? a1 : sel;
      sel = (c == 0) ? a0 : sel;
      sf0 = sel[0] * e0; sf1 = sel[1] * e1;
      sf2 = sel[2] * e2; sf3 = sel[3] * e3;
      unsigned p0 = (unsigned)f2bf(sf0) | ((unsigned)f2bf(sf1) << 16);
      unsigned p1 = (unsigned)f2bf(sf2) | ((unsigned)f2bf(sf3) << 16);
      *reinterpret_cast<unsigned long long*>(
          reinterpret_cast<char*>(&Sb[nb][0]) + 2 * rowbase) =
          ((unsigned long long)p1 << 32) | p0;
      // per-(wave,q) max of the 16 new values: 3 fmax + 2 DPP quad-perm fmax
      float mx = fmaxf(fmaxf(sf0, sf1), fmaxf(sf2, sf3));
      mx = dppmax_quad<0xB1>(mx);   // quad_perm [1,0,3,2]
      mx = dppmax_quad<0x4E>(mx);   // quad_perm [2,3,0,1]
      if (c == 0) wmaxb[nb][w][q] = mx;
      // reload this register pair for t+2 (consumed 2 steps from now)
      if (T + 2 < len) loadU(T + 2, UN);
    }
  };

  const int lenEven = len & ~1;
  for (int t = 0; t < lenEven; t += 2) { step(t, uA); step(t + 1, uB); }
  if (len & 1) step(lenEven, uA);

  // ---- fwd = ln2*(Ms + log2(sum_rows sfin * 2^(trans[end,row]/ln2))) ----
  float P = 0.f;
  if (wr) {
    const float* tE = trans + (size_t)END_ * N_ + rowbase;
    P = sf0 * __builtin_exp2f(tE[0] * RLN2) + sf1 * __builtin_exp2f(tE[1] * RLN2)
      + sf2 * __builtin_exp2f(tE[2] * RLN2) + sf3 * __builtin_exp2f(tE[3] * RLN2);
    P += __shfl_xor(P, 1, 64);  P += __shfl_xor(P, 2, 64);
    P += __shfl_xor(P, 16, 64); P += __shfl_xor(P, 32, 64);
  }
  float G = gold;
#pragma unroll
  for (int o = 32; o > 0; o >>= 1) G += __shfl_xor(G, o, 64);
  if (l == 0) { redP[w] = P; redG[w] = G; }
  __syncthreads();
  if (tid == 0) {
    float Ps = (redP[0] + redP[1]) + (redP[2] + redP[3]);
    float Gs = (redG[0] + redG[1]) + (redG[2] + redG[3]);
    int last = tags[b * T_ + (len - 1)];
    out[b] = LN2f * (Ms + __log2f(Ps)) - (Gs + trans[(size_t)END_ * N_ + last]);
  }
}

extern "C" void kernel_launch(void* const* d_in, const int* in_sizes, int n_in,
                              void* d_out, int out_size, void* d_ws, size_t ws_size,
                              hipStream_t stream) {
  const float* unary   = (const float*)d_in[0];
  const int*   tags    = (const int*)d_in[1];
  const int*   lengths = (const int*)d_in[2];
  const float* trans   = (const float*)d_in[3];
  float*       out     = (float*)d_out;
  hipLaunchKernelGGL(crf_fwd, dim3(B_), dim3(256), 0, stream,
                     unary, tags, lengths, trans, out);
}